// Round 10
// baseline (282.273 us; speedup 1.0000x reference)
//
#include <hip/hip_runtime.h>
#include <cstdint>

typedef __bf16 bf16;
typedef __attribute__((ext_vector_type(8))) __bf16 bf16x8;
typedef __attribute__((ext_vector_type(4))) __bf16 bf16x4;
typedef __attribute__((ext_vector_type(4))) float f32x4;

#define T_TOK 8192
#define IN_F  2048
#define OUT_F 2048
#define GATE_N 128    // E * GK = 8 * 16
#define Z_COLS 256    // svh rows (8 experts x 32)
#define A2C 320       // 256 zw + 8 w + 1 one + 55 zero pad
#define K2_TOT 2368   // 2048 + 320
#define GATE_KS 4     // split-K slices for fp32 gate GEMM (fallback path)
#define BP_R  512     // packed B rows: 256 Wz + 128 gh + 128 gl
#define XBL_LD 4096   // xbl row stride: [xh | xl]

// ---- workspace layout, UNIFIED path (bytes) ----
#define WS_U_XBL 0                    // bf16 xbl  8192*4096*2 = 67108864  [xh|xl]
#define WS_U_GG  67108864             // fp32 Gg   8192*384*4  = 12582912  (3 components)
#define WS_U_A2  79691776             // bf16 A2   8192*320*2  =  5242880
#define WS_U_B2  84934656             // bf16 B2   2048*320*2  =  1310720
#define WS_U_BP  86245376             // bf16 Bp   512*2048*2  =  2097152
#define WS_U_WB  88342528             // bf16 Wb   2048*2048*2 =  8388608
#define WS_U_TOTAL 96731136ULL

// ---- workspace layout, FALLBACK path (known-good 53.7 MB) ----
#define WS_F_XB  0
#define WS_F_GG  33554432
#define WS_F_A2  37748736
#define WS_F_B2  42991616
#define WS_F_WZ  44302336
#define WS_F_WB  45350912

// async 16B global->LDS; LDS dest is wave-uniform base, HW scatters lane i at
// base + i*16 (m104/m108). R1-proven incantation.
__device__ __forceinline__ void async_cp16(const bf16* g, bf16* l) {
  __builtin_amdgcn_global_load_lds(
      (const __attribute__((address_space(1))) void*)reinterpret_cast<uintptr_t>(g),
      (__attribute__((address_space(3))) void*)(uint32_t)reinterpret_cast<uintptr_t>(l),
      16, 0, 0);
}

// Convert fp32 inputs to bf16 workspace tensors.
// unified=1: xout = xbl[8192][4096] rows [xh | xl] (lo half = bf16 residual);
//            WzBp = Bp[512][2048] = rows [Wz; gh; gl] (no padding).
// unified=0: xout = xb[8192][2048] (hi only); WzBp = Wz[256][2048].
__global__ void prep_kernel(const float* __restrict__ x, const float* __restrict__ W,
                            const float* __restrict__ svh,
                            const float* __restrict__ u, const float* __restrict__ eb,
                            const float* __restrict__ b, const float* __restrict__ gw,
                            bf16* __restrict__ xout, bf16* __restrict__ Wb,
                            bf16* __restrict__ WzBp, bf16* __restrict__ B2,
                            int unified) {
  const int idx = blockIdx.x * 256 + threadIdx.x;
  const int nt  = gridDim.x * 256;

  const int nx4 = (T_TOK * IN_F) / 4;
  for (int i = idx; i < nx4; i += nt) {
    const float4 v = ((const float4*)x)[i];
    bf16x4 o = {(bf16)v.x, (bf16)v.y, (bf16)v.z, (bf16)v.w};
    if (unified) {
      const int t = i >> 9;            // 512 float4 per 2048-wide row
      const int c = (i & 511) << 2;
      *(bf16x4*)&xout[(size_t)t * XBL_LD + c] = o;
      bf16x4 l = {(bf16)(v.x - (float)o.x), (bf16)(v.y - (float)o.y),
                  (bf16)(v.z - (float)o.z), (bf16)(v.w - (float)o.w)};
      *(bf16x4*)&xout[(size_t)t * XBL_LD + IN_F + c] = l;
    } else {
      *(bf16x4*)&xout[(size_t)i * 4] = o;
    }
  }

  const int nw4 = (OUT_F * IN_F) / 4;
  for (int i = idx; i < nw4; i += nt) {
    const float4 v = ((const float4*)W)[i];
    bf16x4 o = {(bf16)v.x, (bf16)v.y, (bf16)v.z, (bf16)v.w};
    *(bf16x4*)&Wb[(size_t)i * 4] = o;
  }

  if (unified) {
    // Bp[512][2048]: r<256 -> svh_r; 256..383 -> gh_{r-256}; 384..511 -> gl_{r-384}
    const int nbp4 = BP_R * (IN_F / 4);
    for (int i = idx; i < nbp4; i += nt) {
      const int r  = i >> 9;           // 512 float4 per 2048-wide row
      const int jc = (i & 511) << 2;
      bf16x4 o;
      if (r < 256) {
        const float4 v = *(const float4*)(svh + (size_t)r * IN_F + jc);
        o = bf16x4{(bf16)v.x, (bf16)v.y, (bf16)v.z, (bf16)v.w};
      } else if (r < 384) {
        const float4 v = *(const float4*)(gw + (size_t)(r - 256) * IN_F + jc);
        o = bf16x4{(bf16)v.x, (bf16)v.y, (bf16)v.z, (bf16)v.w};
      } else {
        const float4 v = *(const float4*)(gw + (size_t)(r - 384) * IN_F + jc);
        bf16x4 h = {(bf16)v.x, (bf16)v.y, (bf16)v.z, (bf16)v.w};
        o = bf16x4{(bf16)(v.x - (float)h.x), (bf16)(v.y - (float)h.y),
                   (bf16)(v.z - (float)h.z), (bf16)(v.w - (float)h.w)};
      }
      *(bf16x4*)&WzBp[(size_t)i * 4] = o;
    }
  } else {
    const int nz4 = (Z_COLS * IN_F) / 4;   // svh flat [256][2048]
    for (int i = idx; i < nz4; i += nt) {
      const float4 v = ((const float4*)svh)[i];
      bf16x4 o = {(bf16)v.x, (bf16)v.y, (bf16)v.z, (bf16)v.w};
      *(bf16x4*)&WzBp[(size_t)i * 4] = o;
    }
  }

  // B2[o][j]: j<256 -> u[e=j>>5][o][k=j&31]; 256..263 -> eb[j-256][o]; 264 -> b[o]; else 0
  for (int i = idx; i < OUT_F * A2C; i += nt) {
    const int o = i / A2C, j = i - o * A2C;
    float v;
    if (j < 256) {
      const int e = j >> 5, k = j & 31;
      v = u[((size_t)(e * OUT_F + o)) * 32 + k];
    } else if (j < 264) {
      v = eb[(size_t)(j - 256) * OUT_F + o];
    } else if (j == 264) {
      v = b[o];
    } else {
      v = 0.f;
    }
    B2[i] = (bf16)v;
  }
}

// fp32 VALU gate GEMM fallback (only used if ws_size can't fit the unified
// buffers). Split-K x4 (blockIdx.z), atomicAdd epilogue into zeroed Gg.
__global__ __launch_bounds__(256) void vgemm_gate(
    const float* __restrict__ x, const float* __restrict__ gw,
    float* __restrict__ Gg) {
  __shared__ float As[64][37];
  __shared__ float Bs[64][37];
  const int tid = threadIdx.x;
  const int tx = tid & 15, ty = tid >> 4;
  const int gm0 = blockIdx.y * 64, gn0 = blockIdx.x * 64;
  const int kbeg = blockIdx.z * (IN_F / GATE_KS);
  const int kend = kbeg + (IN_F / GATE_KS);

  float acc[4][4] = {};
  for (int k0 = kbeg; k0 < kend; k0 += 32) {
    __syncthreads();
#pragma unroll
    for (int it = 0; it < 2; ++it) {
      const int idx = it * 256 + tid;
      const int r = idx >> 3, c4 = (idx & 7) * 4;
      const float4 av = *(const float4*)(x + (size_t)(gm0 + r) * IN_F + k0 + c4);
      As[r][c4 + 0] = av.x; As[r][c4 + 1] = av.y;
      As[r][c4 + 2] = av.z; As[r][c4 + 3] = av.w;
      const float4 bv = *(const float4*)(gw + (size_t)(gn0 + r) * IN_F + k0 + c4);
      Bs[r][c4 + 0] = bv.x; Bs[r][c4 + 1] = bv.y;
      Bs[r][c4 + 2] = bv.z; Bs[r][c4 + 3] = bv.w;
    }
    __syncthreads();
#pragma unroll 4
    for (int k = 0; k < 32; ++k) {
      float a[4], bb[4];
#pragma unroll
      for (int i = 0; i < 4; ++i) a[i] = As[4 * ty + i][k];
#pragma unroll
      for (int j = 0; j < 4; ++j) bb[j] = Bs[4 * tx + j][k];
#pragma unroll
      for (int i = 0; i < 4; ++i)
#pragma unroll
        for (int j = 0; j < 4; ++j) acc[i][j] += a[i] * bb[j];
    }
  }
#pragma unroll
  for (int i = 0; i < 4; ++i)
#pragma unroll
    for (int j = 0; j < 4; ++j)
      atomicAdd(&Gg[(size_t)(gm0 + 4 * ty + i) * 128 + (gn0 + 4 * tx + j)],
                acc[i][j]);
}

// MEGA GEMM: one dispatch, 1664 blocks, two block roles, work-balanced
// (68.7 vs 67.1 MF/block), both K=2048 / 32 K-tiles / m97 inner structure.
//  role BIG (1024 blocks): out[128x128 tile] = xh @ Wb^T (fp32 store, no
//    bias — gemm_add contributes A2@B2 which carries b/eb via the A2C trick).
//  role UNI (640 blocks, 128x64 tiles over C[8192][640]):
//    cols   0..255 : A=xh, B=Bp[n0]      (Wz)  -> bf16 A2[.][col]
//    cols 256..511 : A=xh, B=Bp[n0]      (gh/gl) -> fp32 Gg[.][col-256]
//    cols 512..639 : A=xl, B=Bp[n0-256]  (gh)  -> fp32 Gg[.][col-256]
// Role split AFTER the XCD-chunked swizzle (1664 % 8 == 0) so the 6.5
// blocks/CU mix fills the machine (~93% slot utilization — fixes R9's 62.5%).
__global__ __launch_bounds__(256, 2) void mega_gemm(
    const bf16* __restrict__ xbl, const bf16* __restrict__ Wb,
    const bf16* __restrict__ Bp,
    float* __restrict__ out, float* __restrict__ Gg, bf16* __restrict__ A2) {
  constexpr int BK = 64;
  __shared__ __align__(16) bf16 As[128 * BK];   // 16 KB
  __shared__ __align__(16) bf16 Bs[128 * BK];   // 16 KB (uni uses first 8 KB)

  const int tid  = threadIdx.x;
  const int lane = tid & 63;
  const int ml   = lane & 15;
  const int q    = lane >> 4;
  const int wave = tid >> 6;

  int lin = blockIdx.x;
  lin = (lin & 7) * 208 + (lin >> 3);           // 1664 = 8 x 208, bijective

  if (lin < 1024) {
    // ---------------- role BIG ----------------
    const int gm0 = (lin >> 4) * 128;           // 64 row-tiles
    const int gn0 = (lin & 15) * 128;           // 16 col-tiles
    const int wr = wave >> 1, wc = wave & 1;
    const int wm0 = wr * 64, wn0 = wc * 64;

    f32x4 acc[4][4];
    const f32x4 zero = {0.f, 0.f, 0.f, 0.f};
#pragma unroll
    for (int i = 0; i < 4; ++i)
#pragma unroll
      for (int j = 0; j < 4; ++j) acc[i][j] = zero;

    for (int kt = 0; kt < IN_F / BK; ++kt) {
      const int k0 = kt * BK;
      __syncthreads();
#pragma unroll
      for (int it = 0; it < 4; ++it) {          // A: 128 rows * 8 chunks / 256
        const int Cb = it * 256 + wave * 64;
        const int C  = Cb + lane;
        const int m  = C >> 3;
        const int jg = (C & 7) ^ (m & 7);
        async_cp16(xbl + (size_t)(gm0 + m) * XBL_LD + k0 + jg * 8, &As[Cb * 8]);
      }
#pragma unroll
      for (int it = 0; it < 4; ++it) {          // B: 128 rows of Wb
        const int Cb = it * 256 + wave * 64;
        const int C  = Cb + lane;
        const int n  = C >> 3;
        const int jg = (C & 7) ^ (n & 7);
        async_cp16(Wb + (size_t)(gn0 + n) * IN_F + k0 + jg * 8, &Bs[Cb * 8]);
      }
      __syncthreads();
#pragma unroll
      for (int s = 0; s < 2; ++s) {
        bf16x8 af[4], bfr[4];
#pragma unroll
        for (int i = 0; i < 4; ++i) {
          const int m = wm0 + i * 16 + ml;
          const int j = (s * 4 + q) ^ (m & 7);
          af[i] = *(const bf16x8*)&As[(m * 8 + j) * 8];
        }
#pragma unroll
        for (int jn = 0; jn < 4; ++jn) {
          const int n = wn0 + jn * 16 + ml;
          const int j = (s * 4 + q) ^ (n & 7);
          bfr[jn] = *(const bf16x8*)&Bs[(n * 8 + j) * 8];
        }
#pragma unroll
        for (int i = 0; i < 4; ++i)
#pragma unroll
          for (int jn = 0; jn < 4; ++jn)
            acc[i][jn] = __builtin_amdgcn_mfma_f32_16x16x32_bf16(af[i], bfr[jn], acc[i][jn], 0, 0, 0);
      }
    }

#pragma unroll
    for (int i = 0; i < 4; ++i) {
#pragma unroll
      for (int jn = 0; jn < 4; ++jn) {
        const int row = gm0 + wm0 + i * 16 + q * 4;
        const int col = gn0 + wn0 + jn * 16 + ml;
#pragma unroll
        for (int r = 0; r < 4; ++r)
          out[(size_t)(row + r) * OUT_F + col] = acc[i][jn][r];
      }
    }
  } else {
    // ---------------- role UNI (R5-proven 128x64 body) ----------------
    const int t   = lin - 1024;
    const int gm0 = (t / 10) * 128;
    const int n0  = (t % 10) * 64;
    const int aoff  = (n0 >= 512) ? IN_F : 0;
    const int brow0 = (n0 >= 512) ? n0 - 256 : n0;

    const int wr = wave >> 1, wc = wave & 1;
    const int wm0 = wr * 64, wn0 = wc * 32;

    f32x4 acc[4][2];
    const f32x4 zero = {0.f, 0.f, 0.f, 0.f};
#pragma unroll
    for (int i = 0; i < 4; ++i)
#pragma unroll
      for (int j = 0; j < 2; ++j) acc[i][j] = zero;

    for (int kt = 0; kt < IN_F / BK; ++kt) {
      const int k0 = kt * BK;
      __syncthreads();
#pragma unroll
      for (int it = 0; it < 4; ++it) {          // A: 128 rows
        const int Cb = it * 256 + wave * 64;
        const int C  = Cb + lane;
        const int m  = C >> 3;
        const int jg = (C & 7) ^ (m & 7);
        async_cp16(xbl + (size_t)(gm0 + m) * XBL_LD + aoff + k0 + jg * 8, &As[Cb * 8]);
      }
#pragma unroll
      for (int it = 0; it < 2; ++it) {          // B: 64 rows of Bp
        const int Cb = it * 256 + wave * 64;
        const int C  = Cb + lane;
        const int n  = C >> 3;
        const int jg = (C & 7) ^ (n & 7);
        async_cp16(Bp + (size_t)(brow0 + n) * IN_F + k0 + jg * 8, &Bs[Cb * 8]);
      }
      __syncthreads();
#pragma unroll
      for (int s = 0; s < 2; ++s) {
        bf16x8 af[4], bfr[2];
#pragma unroll
        for (int i = 0; i < 4; ++i) {
          const int m = wm0 + i * 16 + ml;
          const int j = (s * 4 + q) ^ (m & 7);
          af[i] = *(const bf16x8*)&As[(m * 8 + j) * 8];
        }
#pragma unroll
        for (int jn = 0; jn < 2; ++jn) {
          const int n = wn0 + jn * 16 + ml;
          const int j = (s * 4 + q) ^ (n & 7);
          bfr[jn] = *(const bf16x8*)&Bs[(n * 8 + j) * 8];
        }
#pragma unroll
        for (int i = 0; i < 4; ++i)
#pragma unroll
          for (int jn = 0; jn < 2; ++jn)
            acc[i][jn] = __builtin_amdgcn_mfma_f32_16x16x32_bf16(af[i], bfr[jn], acc[i][jn], 0, 0, 0);
      }
    }

#pragma unroll
    for (int i = 0; i < 4; ++i) {
#pragma unroll
      for (int jn = 0; jn < 2; ++jn) {
        const int row = gm0 + wm0 + i * 16 + q * 4;
        const int col = n0 + wn0 + jn * 16 + ml;
#pragma unroll
        for (int r = 0; r < 4; ++r) {
          if (n0 < 256)
            A2[(size_t)(row + r) * A2C + col] = (bf16)acc[i][jn][r];
          else
            Gg[(size_t)(row + r) * 384 + (col - 256)] = acc[i][jn][r];
        }
      }
    }
  }
}

// out += A2(routed) @ B2^T, K = A2C = 320 (5 K-tiles). 1024 blocks of
// 128x128, m97 inner structure, fp32 read-modify-write epilogue (each
// element owned by exactly one block; out fully rewritten by mega each
// iteration, so replay-safe). Memory-bound (~135 MB traffic).
__global__ __launch_bounds__(256, 2) void gemm_add(
    const bf16* __restrict__ A2, const bf16* __restrict__ B2,
    float* __restrict__ out) {
  constexpr int BK = 64;
  __shared__ __align__(16) bf16 As[128 * BK];
  __shared__ __align__(16) bf16 Bs[128 * BK];

  const int tid  = threadIdx.x;
  const int lane = tid & 63;
  const int ml   = lane & 15;
  const int q    = lane >> 4;
  const int wave = tid >> 6;

  int lin = blockIdx.x;                         // 1024
  lin = (lin & 7) * 128 + (lin >> 3);           // XCD-chunked swizzle
  const int gm0 = (lin >> 4) * 128;
  const int gn0 = (lin & 15) * 128;

  const int wr = wave >> 1, wc = wave & 1;
  const int wm0 = wr * 64, wn0 = wc * 64;

  f32x4 acc[4][4];
  const f32x4 zero = {0.f, 0.f, 0.f, 0.f};
#pragma unroll
  for (int i = 0; i < 4; ++i)
#pragma unroll
    for (int j = 0; j < 4; ++j) acc[i][j] = zero;

  for (int kt = 0; kt < A2C / BK; ++kt) {       // 5 K-tiles
    const int k0 = kt * BK;
    __syncthreads();
#pragma unroll
    for (int it = 0; it < 4; ++it) {
      const int Cb = it * 256 + wave * 64;
      const int C  = Cb + lane;
      const int m  = C >> 3;
      const int jg = (C & 7) ^ (m & 7);
      async_cp16(A2 + (size_t)(gm0 + m) * A2C + k0 + jg * 8, &As[Cb * 8]);
    }
#pragma unroll
    for (int it = 0; it < 4; ++it) {
      const int Cb = it * 256 + wave * 64;
      const int C  = Cb + lane;
      const int n  = C >> 3;
      const int jg = (C & 7) ^ (n & 7);
      async_cp16(B2 + (size_t)(gn0 + n) * A2C + k0 + jg * 8, &Bs[Cb * 8]);
    }
    __syncthreads();
#pragma unroll
    for (int s = 0; s < 2; ++s) {
      bf16x8 af[4], bfr[4];
#pragma unroll
      for (int i = 0; i < 4; ++i) {
        const int m = wm0 + i * 16 + ml;
        const int j = (s * 4 + q) ^ (m & 7);
        af[i] = *(const bf16x8*)&As[(m * 8 + j) * 8];
      }
#pragma unroll
      for (int jn = 0; jn < 4; ++jn) {
        const int n = wn0 + jn * 16 + ml;
        const int j = (s * 4 + q) ^ (n & 7);
        bfr[jn] = *(const bf16x8*)&Bs[(n * 8 + j) * 8];
      }
#pragma unroll
      for (int i = 0; i < 4; ++i)
#pragma unroll
        for (int jn = 0; jn < 4; ++jn)
          acc[i][jn] = __builtin_amdgcn_mfma_f32_16x16x32_bf16(af[i], bfr[jn], acc[i][jn], 0, 0, 0);
    }
  }

#pragma unroll
  for (int i = 0; i < 4; ++i) {
#pragma unroll
    for (int jn = 0; jn < 4; ++jn) {
      const int row = gm0 + wm0 + i * 16 + q * 4;
      const int col = gn0 + wn0 + jn * 16 + ml;
#pragma unroll
      for (int r = 0; r < 4; ++r)
        out[(size_t)(row + r) * OUT_F + col] += acc[i][jn][r];
    }
  }
}

// bf16 MFMA GEMM (async global_load_lds staging, m97 rung) — FALLBACK only.
// THREE K-segments on absolute k. OUTMODE: 0 = fp32 store, 1 = bf16 store.
template <int BM, int BN, int OUTMODE>
__global__ __launch_bounds__(256, 2) void gemm_bt(
    const bf16* __restrict__ A0, int lda0, const bf16* __restrict__ A1, int lda1,
    const bf16* __restrict__ A2p, int lda2,
    const bf16* __restrict__ B0, int ldb0, const bf16* __restrict__ B1, int ldb1,
    const bf16* __restrict__ B2p, int ldb2,
    void* __restrict__ Cout, int ldc, int K1, int K2, int Ktot) {
  constexpr int BK = 64;
  __shared__ __align__(16) bf16 As[BM * BK];
  __shared__ __align__(16) bf16 Bs[BN * BK];

  const int tid  = threadIdx.x;
  const int lane = tid & 63;
  const int ml   = lane & 15;
  const int q    = lane >> 4;
  const int wave = tid >> 6;

  const int gx  = gridDim.x;
  const int nwg = gx * gridDim.y;
  int lin = blockIdx.y * gx + blockIdx.x;
  if ((nwg & 7) == 0) lin = (lin & 7) * (nwg >> 3) + (lin >> 3);
  const int gm0 = (lin / gx) * BM;
  const int gn0 = (lin % gx) * BN;

  constexpr int FM = BM / 32;
  constexpr int FN = BN / 32;
  const int wr  = wave >> 1, wc = wave & 1;
  const int wm0 = wr * (BM / 2);
  const int wn0 = wc * (BN / 2);

  f32x4 acc[FM][FN];
  const f32x4 zero = {0.f, 0.f, 0.f, 0.f};
#pragma unroll
  for (int i = 0; i < FM; ++i)
#pragma unroll
    for (int j = 0; j < FN; ++j) acc[i][j] = zero;

  constexpr int NCA = BM * 8 / 256;
  constexpr int NCB = BN * 8 / 256;

  const int nkt = Ktot / BK;
  for (int kt = 0; kt < nkt; ++kt) {
    const int k0 = kt * BK;
    const bf16* Ap; int lda, ka;
    const bf16* Bp; int ldb, kb;
    if (k0 < K1) {
      Ap = A0;  lda = lda0; ka = k0;      Bp = B0;  ldb = ldb0; kb = k0;
    } else if (k0 < K2) {
      Ap = A1;  lda = lda1; ka = k0 - K1; Bp = B1;  ldb = ldb1; kb = k0 - K1;
    } else {
      Ap = A2p; lda = lda2; ka = k0 - K2; Bp = B2p; ldb = ldb2; kb = k0 - K2;
    }

    __syncthreads();

#pragma unroll
    for (int it = 0; it < NCA; ++it) {
      const int Cb = it * 256 + wave * 64;
      const int C  = Cb + lane;
      const int m  = C >> 3;
      const int jg = (C & 7) ^ (m & 7);
      async_cp16(Ap + (size_t)(gm0 + m) * lda + ka + jg * 8, &As[Cb * 8]);
    }
#pragma unroll
    for (int it = 0; it < NCB; ++it) {
      const int Cb = it * 256 + wave * 64;
      const int C  = Cb + lane;
      const int n  = C >> 3;
      const int jg = (C & 7) ^ (n & 7);
      async_cp16(Bp + (size_t)(gn0 + n) * ldb + kb + jg * 8, &Bs[Cb * 8]);
    }

    __syncthreads();

#pragma unroll
    for (int s = 0; s < 2; ++s) {
      bf16x8 af[FM], bfr[FN];
#pragma unroll
      for (int i = 0; i < FM; ++i) {
        const int m = wm0 + i * 16 + ml;
        const int j = (s * 4 + q) ^ (m & 7);
        af[i] = *(const bf16x8*)&As[(m * 8 + j) * 8];
      }
#pragma unroll
      for (int jn = 0; jn < FN; ++jn) {
        const int n = wn0 + jn * 16 + ml;
        const int j = (s * 4 + q) ^ (n & 7);
        bfr[jn] = *(const bf16x8*)&Bs[(n * 8 + j) * 8];
      }
#pragma unroll
      for (int i = 0; i < FM; ++i)
#pragma unroll
        for (int jn = 0; jn < FN; ++jn)
          acc[i][jn] = __builtin_amdgcn_mfma_f32_16x16x32_bf16(af[i], bfr[jn], acc[i][jn], 0, 0, 0);
    }
  }

#pragma unroll
  for (int i = 0; i < FM; ++i) {
#pragma unroll
    for (int jn = 0; jn < FN; ++jn) {
      const int row = gm0 + wm0 + i * 16 + q * 4;
      const int col = gn0 + wn0 + jn * 16 + ml;
#pragma unroll
      for (int r = 0; r < 4; ++r) {
        if constexpr (OUTMODE == 1)
          ((bf16*)Cout)[(size_t)(row + r) * ldc + col] = (bf16)acc[i][jn][r];
        else
          ((float*)Cout)[(size_t)(row + r) * ldc + col] = acc[i][jn][r];
      }
    }
  }
}

// One wave per token: fp32 gate logits (sum of ncomp 128-wide components in a
// gld-wide Gg row) -> exact top-2 softmax; scale the bf16 z values already
// sitting in A2[t][0:256] in-place; fill cols 256..319.
__global__ void router_kernel(const float* __restrict__ Gg, bf16* __restrict__ A2,
                              int gld, int ncomp) {
  const int wave = threadIdx.x >> 6, lane = threadIdx.x & 63;
  const int t = blockIdx.x * 4 + wave;
  const float* g = Gg + (size_t)t * gld;
  float g1 = 0.f, g2 = 0.f;
  for (int cc = 0; cc < ncomp; ++cc) {
    g1 += g[cc * 128 + lane];
    g2 += g[cc * 128 + 64 + lane];
  }
  float s1 = g1 * g1, s2 = g2 * g2;
#pragma unroll
  for (int off = 1; off < 16; off <<= 1) {
    s1 += __shfl_xor(s1, off, 64);
    s2 += __shfl_xor(s2, off, 64);
  }
  float lg[8];
#pragma unroll
  for (int e = 0; e < 4; ++e) {
    lg[e]     = sqrtf(__shfl(s1, e * 16, 64));
    lg[e + 4] = sqrtf(__shfl(s2, e * 16, 64));
  }
  int i1 = 0; float l1 = lg[0];
#pragma unroll
  for (int e = 1; e < 8; ++e) if (lg[e] > l1) { l1 = lg[e]; i1 = e; }
  int i2 = -1; float l2 = -1e30f;
#pragma unroll
  for (int e = 0; e < 8; ++e) if (e != i1 && lg[e] > l2) { l2 = lg[e]; i2 = e; }
  const float w1 = 1.f / (1.f + expf(l2 - l1));  // exact top-2 softmax renorm
  const float w2 = 1.f - w1;

  bf16* a2 = A2 + (size_t)t * A2C;
#pragma unroll
  for (int c0 = 0; c0 < A2C; c0 += 64) {
    const int c = c0 + lane;
    float v;
    if (c < 256) {
      const int we = c >> 5;
      const float wsel = (we == i1) ? w1 : ((we == i2) ? w2 : 0.f);
      v = (float)a2[c] * wsel;   // z (bf16, written by mega) scaled in place
    } else if (c < 264) {
      const int we = c - 256;
      v = (we == i1) ? w1 : ((we == i2) ? w2 : 0.f);
    } else if (c == 264) {
      v = 1.f;
    } else {
      v = 0.f;
    }
    a2[c] = (bf16)v;
  }
}

extern "C" void kernel_launch(void* const* d_in, const int* in_sizes, int n_in,
                              void* d_out, int out_size, void* d_ws, size_t ws_size,
                              hipStream_t stream) {
  // size-based dispatch; u/svh share 524288: first = u, second = svh (dict order)
  const float *x = nullptr, *W = nullptr, *b = nullptr, *gw = nullptr;
  const float *u = nullptr, *svh = nullptr, *eb = nullptr;
  int seen524 = 0;
  for (int i = 0; i < n_in; ++i) {
    switch (in_sizes[i]) {
      case 16777216: x  = (const float*)d_in[i]; break;
      case 4194304:  W  = (const float*)d_in[i]; break;
      case 2048:     b  = (const float*)d_in[i]; break;
      case 262144:   gw = (const float*)d_in[i]; break;
      case 524288:   if (seen524++ == 0) u = (const float*)d_in[i];
                     else                svh = (const float*)d_in[i];
                     break;
      case 16384:    eb = (const float*)d_in[i]; break;
      default: break;  // top_k (size 1)
    }
  }
  float* out = (float*)d_out;   // fp32 output (confirmed round 6)

  char* ws = (char*)d_ws;
  // Unified path needs 96.7 MB; fall back to the known-good 53.7 MB layout
  // with the fp32 VALU gate if the harness gave us less.
  const bool unified = (ws_size >= WS_U_TOTAL);

  if (unified) {
    bf16*  xbl = (bf16*)(ws + WS_U_XBL);
    float* Gg  = (float*)(ws + WS_U_GG);
    bf16*  A2  = (bf16*)(ws + WS_U_A2);
    bf16*  B2  = (bf16*)(ws + WS_U_B2);
    bf16*  Bp  = (bf16*)(ws + WS_U_BP);
    bf16*  Wb  = (bf16*)(ws + WS_U_WB);

    prep_kernel<<<1024, 256, 0, stream>>>(x, W, svh, u, eb, b, gw,
                                          xbl, Wb, Bp, B2, 1);

    // One dispatch: out = xh@Wb (1024 tiles) ∥ z/gate small GEMM (640 tiles).
    mega_gemm<<<1664, 256, 0, stream>>>(xbl, Wb, Bp, out, Gg, A2);

    router_kernel<<<T_TOK / 4, 256, 0, stream>>>(Gg, A2, 384, 3);

    // out += A2@B2^T (moe + eb + b via the A2C packing), K=320 RMW.
    gemm_add<<<1024, 256, 0, stream>>>(A2, B2, out);
  } else {
    bf16*  xb = (bf16*)(ws + WS_F_XB);
    float* Gg = (float*)(ws + WS_F_GG);
    bf16*  A2 = (bf16*)(ws + WS_F_A2);
    bf16*  B2 = (bf16*)(ws + WS_F_B2);
    bf16*  Wz = (bf16*)(ws + WS_F_WZ);
    bf16*  Wb = (bf16*)(ws + WS_F_WB);

    prep_kernel<<<1024, 256, 0, stream>>>(x, W, svh, u, eb, b, gw,
                                          xb, Wb, Wz, B2, 0);

    hipMemsetAsync(Gg, 0, (size_t)T_TOK * GATE_N * 4, stream);
    vgemm_gate<<<dim3(2, T_TOK / 64, GATE_KS), 256, 0, stream>>>(x, gw, Gg);
    gemm_bt<64, 64, 1><<<dim3(Z_COLS / 64, T_TOK / 64), 256, 0, stream>>>(
        xb, IN_F, xb, IN_F, xb, IN_F, Wz, IN_F, Wz, IN_F, Wz, IN_F,
        (void*)A2, A2C, IN_F, IN_F, IN_F);

    router_kernel<<<T_TOK / 4, 256, 0, stream>>>(Gg, A2, 128, 1);

    gemm_bt<128, 128, 0><<<dim3(OUT_F / 128, T_TOK / 128), 256, 0, stream>>>(
        xb, IN_F, A2, A2C, A2, A2C, Wb, IN_F, B2, A2C, B2, A2C,
        (void*)out, OUT_F, IN_F, K2_TOT, K2_TOT);
  }
}

// Round 11
// 255.985 us; speedup vs baseline: 1.1027x; 1.1027x over previous
//
#include <hip/hip_runtime.h>
#include <cstdint>

typedef __bf16 bf16;
typedef __attribute__((ext_vector_type(8))) __bf16 bf16x8;
typedef __attribute__((ext_vector_type(4))) __bf16 bf16x4;
typedef __attribute__((ext_vector_type(4))) float f32x4;

#define T_TOK 8192
#define IN_F  2048
#define OUT_F 2048
#define GATE_N 128    // E * GK = 8 * 16
#define Z_COLS 256    // svh rows (8 experts x 32)
#define A2C 320       // 256 zw + 8 w + 1 one + 55 zero pad
#define K2_TOT 2368   // 2048 + 320
#define GATE_KS 4     // split-K slices for fp32 gate GEMM (fallback path)
#define BP_R  512     // packed B rows: 256 Wz + 128 gh + 128 gl
#define XBL_LD 4096   // xbl row stride: [xh | xl]

// ---- workspace layout, UNIFIED path (bytes) ----
#define WS_U_XBL 0                    // bf16 xbl  8192*4096*2 = 67108864  [xh|xl]
#define WS_U_GG  67108864             // fp32 Gg   8192*384*4  = 12582912  (3 components)
#define WS_U_A2  79691776             // bf16 A2   8192*320*2  =  5242880
#define WS_U_B2  84934656             // bf16 B2   2048*320*2  =  1310720
#define WS_U_BP  86245376             // bf16 Bp   512*2048*2  =  2097152
#define WS_U_WB  88342528             // bf16 Wb   2048*2048*2 =  8388608
#define WS_U_TOTAL 96731136ULL

// ---- workspace layout, FALLBACK path (known-good 53.7 MB) ----
#define WS_F_XB  0
#define WS_F_GG  33554432
#define WS_F_A2  37748736
#define WS_F_B2  42991616
#define WS_F_WZ  44302336
#define WS_F_WB  45350912

// async 16B global->LDS; LDS dest is wave-uniform base, HW scatters lane i at
// base + i*16 (m104/m108). R1-proven incantation.
__device__ __forceinline__ void async_cp16(const bf16* g, bf16* l) {
  __builtin_amdgcn_global_load_lds(
      (const __attribute__((address_space(1))) void*)reinterpret_cast<uintptr_t>(g),
      (__attribute__((address_space(3))) void*)(uint32_t)reinterpret_cast<uintptr_t>(l),
      16, 0, 0);
}

// Convert fp32 inputs to bf16 workspace tensors.
// unified=1: xout = xbl[8192][4096] rows [xh | xl] (lo half = bf16 residual);
//            WzBp = Bp[512][2048] = rows [Wz; gh; gl] (no padding).
// unified=0: xout = xb[8192][2048] (hi only); WzBp = Wz[256][2048].
__global__ void prep_kernel(const float* __restrict__ x, const float* __restrict__ W,
                            const float* __restrict__ svh,
                            const float* __restrict__ u, const float* __restrict__ eb,
                            const float* __restrict__ b, const float* __restrict__ gw,
                            bf16* __restrict__ xout, bf16* __restrict__ Wb,
                            bf16* __restrict__ WzBp, bf16* __restrict__ B2,
                            int unified) {
  const int idx = blockIdx.x * 256 + threadIdx.x;
  const int nt  = gridDim.x * 256;

  const int nx4 = (T_TOK * IN_F) / 4;
  for (int i = idx; i < nx4; i += nt) {
    const float4 v = ((const float4*)x)[i];
    bf16x4 o = {(bf16)v.x, (bf16)v.y, (bf16)v.z, (bf16)v.w};
    if (unified) {
      const int t = i >> 9;            // 512 float4 per 2048-wide row
      const int c = (i & 511) << 2;
      *(bf16x4*)&xout[(size_t)t * XBL_LD + c] = o;
      bf16x4 l = {(bf16)(v.x - (float)o.x), (bf16)(v.y - (float)o.y),
                  (bf16)(v.z - (float)o.z), (bf16)(v.w - (float)o.w)};
      *(bf16x4*)&xout[(size_t)t * XBL_LD + IN_F + c] = l;
    } else {
      *(bf16x4*)&xout[(size_t)i * 4] = o;
    }
  }

  const int nw4 = (OUT_F * IN_F) / 4;
  for (int i = idx; i < nw4; i += nt) {
    const float4 v = ((const float4*)W)[i];
    bf16x4 o = {(bf16)v.x, (bf16)v.y, (bf16)v.z, (bf16)v.w};
    *(bf16x4*)&Wb[(size_t)i * 4] = o;
  }

  if (unified) {
    // Bp[512][2048]: r<256 -> svh_r; 256..383 -> gh_{r-256}; 384..511 -> gl_{r-384}
    const int nbp4 = BP_R * (IN_F / 4);
    for (int i = idx; i < nbp4; i += nt) {
      const int r  = i >> 9;           // 512 float4 per 2048-wide row
      const int jc = (i & 511) << 2;
      bf16x4 o;
      if (r < 256) {
        const float4 v = *(const float4*)(svh + (size_t)r * IN_F + jc);
        o = bf16x4{(bf16)v.x, (bf16)v.y, (bf16)v.z, (bf16)v.w};
      } else if (r < 384) {
        const float4 v = *(const float4*)(gw + (size_t)(r - 256) * IN_F + jc);
        o = bf16x4{(bf16)v.x, (bf16)v.y, (bf16)v.z, (bf16)v.w};
      } else {
        const float4 v = *(const float4*)(gw + (size_t)(r - 384) * IN_F + jc);
        bf16x4 h = {(bf16)v.x, (bf16)v.y, (bf16)v.z, (bf16)v.w};
        o = bf16x4{(bf16)(v.x - (float)h.x), (bf16)(v.y - (float)h.y),
                   (bf16)(v.z - (float)h.z), (bf16)(v.w - (float)h.w)};
      }
      *(bf16x4*)&WzBp[(size_t)i * 4] = o;
    }
  } else {
    const int nz4 = (Z_COLS * IN_F) / 4;   // svh flat [256][2048]
    for (int i = idx; i < nz4; i += nt) {
      const float4 v = ((const float4*)svh)[i];
      bf16x4 o = {(bf16)v.x, (bf16)v.y, (bf16)v.z, (bf16)v.w};
      *(bf16x4*)&WzBp[(size_t)i * 4] = o;
    }
  }

  // B2[o][j]: j<256 -> u[e=j>>5][o][k=j&31]; 256..263 -> eb[j-256][o]; 264 -> b[o]; else 0
  for (int i = idx; i < OUT_F * A2C; i += nt) {
    const int o = i / A2C, j = i - o * A2C;
    float v;
    if (j < 256) {
      const int e = j >> 5, k = j & 31;
      v = u[((size_t)(e * OUT_F + o)) * 32 + k];
    } else if (j < 264) {
      v = eb[(size_t)(j - 256) * OUT_F + o];
    } else if (j == 264) {
      v = b[o];
    } else {
      v = 0.f;
    }
    B2[i] = (bf16)v;
  }
}

// fp32 VALU gate GEMM fallback (only used if ws_size can't fit the unified
// buffers). Split-K x4 (blockIdx.z), atomicAdd epilogue into zeroed Gg.
__global__ __launch_bounds__(256) void vgemm_gate(
    const float* __restrict__ x, const float* __restrict__ gw,
    float* __restrict__ Gg) {
  __shared__ float As[64][37];
  __shared__ float Bs[64][37];
  const int tid = threadIdx.x;
  const int tx = tid & 15, ty = tid >> 4;
  const int gm0 = blockIdx.y * 64, gn0 = blockIdx.x * 64;
  const int kbeg = blockIdx.z * (IN_F / GATE_KS);
  const int kend = kbeg + (IN_F / GATE_KS);

  float acc[4][4] = {};
  for (int k0 = kbeg; k0 < kend; k0 += 32) {
    __syncthreads();
#pragma unroll
    for (int it = 0; it < 2; ++it) {
      const int idx = it * 256 + tid;
      const int r = idx >> 3, c4 = (idx & 7) * 4;
      const float4 av = *(const float4*)(x + (size_t)(gm0 + r) * IN_F + k0 + c4);
      As[r][c4 + 0] = av.x; As[r][c4 + 1] = av.y;
      As[r][c4 + 2] = av.z; As[r][c4 + 3] = av.w;
      const float4 bv = *(const float4*)(gw + (size_t)(gn0 + r) * IN_F + k0 + c4);
      Bs[r][c4 + 0] = bv.x; Bs[r][c4 + 1] = bv.y;
      Bs[r][c4 + 2] = bv.z; Bs[r][c4 + 3] = bv.w;
    }
    __syncthreads();
#pragma unroll 4
    for (int k = 0; k < 32; ++k) {
      float a[4], bb[4];
#pragma unroll
      for (int i = 0; i < 4; ++i) a[i] = As[4 * ty + i][k];
#pragma unroll
      for (int j = 0; j < 4; ++j) bb[j] = Bs[4 * tx + j][k];
#pragma unroll
      for (int i = 0; i < 4; ++i)
#pragma unroll
        for (int j = 0; j < 4; ++j) acc[i][j] += a[i] * bb[j];
    }
  }
#pragma unroll
  for (int i = 0; i < 4; ++i)
#pragma unroll
    for (int j = 0; j < 4; ++j)
      atomicAdd(&Gg[(size_t)(gm0 + 4 * ty + i) * 128 + (gn0 + 4 * tx + j)],
                acc[i][j]);
}

// Uniform small GEMM: C[8192][640] tiles of 128x64, ALL with K=2048.
// Per-block operand select by output column group (no padding, no imbalance):
//   cols   0..255 : A=xh, B=Bp rows n0      (Wz)  -> bf16 A2[.][col]
//   cols 256..511 : A=xh, B=Bp rows n0      (gh/gl) -> fp32 Gg[.][col-256]
//   cols 512..639 : A=xl, B=Bp rows n0-256  (gh)  -> fp32 Gg[.][col-256]
// xh/xl live in xbl[8192][4096] as [xh|xl]; xl = column offset 2048.
// m97 inner structure (async_cp16 staging, XOR swizzle); XCD-chunked swizzle.
__global__ __launch_bounds__(256, 2) void uni_gemm(
    const bf16* __restrict__ xbl, const bf16* __restrict__ Bp,
    float* __restrict__ Gg, bf16* __restrict__ A2) {
  constexpr int BM = 128, BN = 64, BK = 64;
  __shared__ __align__(16) bf16 As[BM * BK];
  __shared__ __align__(16) bf16 Bs[BN * BK];

  const int tid  = threadIdx.x;
  const int lane = tid & 63;
  const int ml   = lane & 15;
  const int q    = lane >> 4;
  const int wave = tid >> 6;

  // grid = 640 blocks (10 col-blocks x 64 row-blocks); 640 % 8 == 0.
  int lin = blockIdx.x;
  lin = (lin & 7) * 80 + (lin >> 3);          // XCD-chunked swizzle
  const int gm0 = (lin / 10) * BM;
  const int n0  = (lin % 10) * BN;            // global output col base
  const int aoff  = (n0 >= 512) ? IN_F : 0;   // xl half for comp-3
  const int brow0 = (n0 >= 512) ? n0 - 256 : n0;

  const int wr = wave >> 1, wc = wave & 1;
  const int wm0 = wr * 64, wn0 = wc * 32;

  f32x4 acc[4][2];
  const f32x4 zero = {0.f, 0.f, 0.f, 0.f};
#pragma unroll
  for (int i = 0; i < 4; ++i)
#pragma unroll
    for (int j = 0; j < 2; ++j) acc[i][j] = zero;

  for (int kt = 0; kt < IN_F / BK; ++kt) {
    const int k0 = kt * BK;

    __syncthreads();  // all waves done reading previous tile's LDS

#pragma unroll
    for (int it = 0; it < 4; ++it) {          // A: 128 rows * 8 chunks / 256
      const int Cb = it * 256 + wave * 64;
      const int C  = Cb + lane;
      const int m  = C >> 3;
      const int jg = (C & 7) ^ (m & 7);
      async_cp16(xbl + (size_t)(gm0 + m) * XBL_LD + aoff + k0 + jg * 8, &As[Cb * 8]);
    }
#pragma unroll
    for (int it = 0; it < 2; ++it) {          // B: 64 rows * 8 chunks / 256
      const int Cb = it * 256 + wave * 64;
      const int C  = Cb + lane;
      const int n  = C >> 3;
      const int jg = (C & 7) ^ (n & 7);
      async_cp16(Bp + (size_t)(brow0 + n) * IN_F + k0 + jg * 8, &Bs[Cb * 8]);
    }

    __syncthreads();  // compiler drains vmcnt before s_barrier -> LDS visible

#pragma unroll
    for (int s = 0; s < 2; ++s) {
      bf16x8 af[4], bfr[2];
#pragma unroll
      for (int i = 0; i < 4; ++i) {
        const int m = wm0 + i * 16 + ml;
        const int j = (s * 4 + q) ^ (m & 7);
        af[i] = *(const bf16x8*)&As[(m * 8 + j) * 8];
      }
#pragma unroll
      for (int jn = 0; jn < 2; ++jn) {
        const int n = wn0 + jn * 16 + ml;
        const int j = (s * 4 + q) ^ (n & 7);
        bfr[jn] = *(const bf16x8*)&Bs[(n * 8 + j) * 8];
      }
#pragma unroll
      for (int i = 0; i < 4; ++i)
#pragma unroll
        for (int jn = 0; jn < 2; ++jn)
          acc[i][jn] = __builtin_amdgcn_mfma_f32_16x16x32_bf16(af[i], bfr[jn], acc[i][jn], 0, 0, 0);
    }
  }

  // C/D layout: col=lane&15, row=(lane>>4)*4+reg. n0 group is block-uniform.
#pragma unroll
  for (int i = 0; i < 4; ++i) {
#pragma unroll
    for (int jn = 0; jn < 2; ++jn) {
      const int row = gm0 + wm0 + i * 16 + q * 4;
      const int col = n0 + wn0 + jn * 16 + ml;
#pragma unroll
      for (int r = 0; r < 4; ++r) {
        if (n0 < 256)
          A2[(size_t)(row + r) * A2C + col] = (bf16)acc[i][jn][r];
        else
          Gg[(size_t)(row + r) * 384 + (col - 256)] = acc[i][jn][r];
      }
    }
  }
}

// Big fused GEMM v2: 256x128 tile / BK=64 / 256 threads (4 waves, 2x2 grid).
// Per-wave output 128x64 -> FM=8, FN=4 -> 64 MFMA per wave per K-step (2x the
// 128^2 density, amortizing barrier+staging) while LDS=48KB and ~200 VGPR keep
// 2 blocks/CU (the occupancy the 256^2/8-wave version lost). Grid 16x32 = 512
// blocks = exact 2-per-CU fill, zero tail. Same proven 2-barrier m97 loop.
// Two K-segments: k<K1 -> (A0 lda0, B0 ldb0); else (A1,B1) at col k-K1.
__global__ __launch_bounds__(256, 2) void gemm_big2(
    const bf16* __restrict__ A0, int lda0, const bf16* __restrict__ A1, int lda1,
    const bf16* __restrict__ B0, int ldb0, const bf16* __restrict__ B1, int ldb1,
    float* __restrict__ Cout, int ldc, int K1, int Ktot) {
  constexpr int BM = 256, BN = 128, BK = 64;
  __shared__ __align__(16) bf16 As[BM * BK];   // 32 KB
  __shared__ __align__(16) bf16 Bs[BN * BK];   // 16 KB

  const int tid  = threadIdx.x;
  const int lane = tid & 63;
  const int ml   = lane & 15;
  const int q    = lane >> 4;
  const int wave = tid >> 6;

  // 512 blocks = 32 row-tiles x 16 col-tiles; XCD-chunked swizzle (512%8==0).
  int lin = blockIdx.x;
  lin = (lin & 7) * 64 + (lin >> 3);
  const int gm0 = (lin >> 4) * BM;
  const int gn0 = (lin & 15) * BN;

  const int wr = wave >> 1, wc = wave & 1;     // 2 x 2 wave grid
  const int wm0 = wr * 128, wn0 = wc * 64;     // per-wave 128 x 64

  f32x4 acc[8][4];
  const f32x4 zero = {0.f, 0.f, 0.f, 0.f};
#pragma unroll
  for (int i = 0; i < 8; ++i)
#pragma unroll
    for (int j = 0; j < 4; ++j) acc[i][j] = zero;

  const int nkt = Ktot / BK;
  for (int kt = 0; kt < nkt; ++kt) {
    const int k0 = kt * BK;
    const bf16* Ap; const bf16* Bp; int lda, ldb, ka;
    if (k0 < K1) { Ap = A0; lda = lda0; Bp = B0; ldb = ldb0; ka = k0; }
    else         { Ap = A1; lda = lda1; Bp = B1; ldb = ldb1; ka = k0 - K1; }

    __syncthreads();  // all waves done reading previous tile's LDS

#pragma unroll
    for (int it = 0; it < 8; ++it) {          // A: 256 rows * 8 chunks / 256 thr
      const int Cb = it * 256 + wave * 64;    // wave-uniform chunk base
      const int C  = Cb + lane;
      const int m  = C >> 3;
      const int jg = (C & 7) ^ (m & 7);       // un-swizzle on global side
      async_cp16(Ap + (size_t)(gm0 + m) * lda + ka + jg * 8, &As[Cb * 8]);
    }
#pragma unroll
    for (int it = 0; it < 4; ++it) {          // B: 128 rows * 8 chunks / 256 thr
      const int Cb = it * 256 + wave * 64;
      const int C  = Cb + lane;
      const int n  = C >> 3;
      const int jg = (C & 7) ^ (n & 7);
      async_cp16(Bp + (size_t)(gn0 + n) * ldb + ka + jg * 8, &Bs[Cb * 8]);
    }

    __syncthreads();  // compiler drains vmcnt before s_barrier -> LDS visible

#pragma unroll
    for (int s = 0; s < 2; ++s) {
      bf16x8 af[8], bfr[4];
#pragma unroll
      for (int i = 0; i < 8; ++i) {
        const int m = wm0 + i * 16 + ml;
        const int j = (s * 4 + q) ^ (m & 7);
        af[i] = *(const bf16x8*)&As[(m * 8 + j) * 8];
      }
#pragma unroll
      for (int jn = 0; jn < 4; ++jn) {
        const int n = wn0 + jn * 16 + ml;
        const int j = (s * 4 + q) ^ (n & 7);
        bfr[jn] = *(const bf16x8*)&Bs[(n * 8 + j) * 8];
      }
#pragma unroll
      for (int i = 0; i < 8; ++i)
#pragma unroll
        for (int jn = 0; jn < 4; ++jn)
          acc[i][jn] = __builtin_amdgcn_mfma_f32_16x16x32_bf16(af[i], bfr[jn], acc[i][jn], 0, 0, 0);
    }
  }

  // C/D layout: col=lane&15, row=(lane>>4)*4+reg
#pragma unroll
  for (int i = 0; i < 8; ++i) {
#pragma unroll
    for (int jn = 0; jn < 4; ++jn) {
      const int row = gm0 + wm0 + i * 16 + q * 4;
      const int col = gn0 + wn0 + jn * 16 + ml;
#pragma unroll
      for (int r = 0; r < 4; ++r)
        Cout[(size_t)(row + r) * ldc + col] = acc[i][jn][r];
    }
  }
}

// bf16 MFMA GEMM (async global_load_lds staging, m97 rung) — FALLBACK only.
// THREE K-segments on absolute k. OUTMODE: 0 = fp32 store, 1 = bf16 store.
template <int BM, int BN, int OUTMODE>
__global__ __launch_bounds__(256, 2) void gemm_bt(
    const bf16* __restrict__ A0, int lda0, const bf16* __restrict__ A1, int lda1,
    const bf16* __restrict__ A2p, int lda2,
    const bf16* __restrict__ B0, int ldb0, const bf16* __restrict__ B1, int ldb1,
    const bf16* __restrict__ B2p, int ldb2,
    void* __restrict__ Cout, int ldc, int K1, int K2, int Ktot) {
  constexpr int BK = 64;
  __shared__ __align__(16) bf16 As[BM * BK];
  __shared__ __align__(16) bf16 Bs[BN * BK];

  const int tid  = threadIdx.x;
  const int lane = tid & 63;
  const int ml   = lane & 15;
  const int q    = lane >> 4;
  const int wave = tid >> 6;

  const int gx  = gridDim.x;
  const int nwg = gx * gridDim.y;
  int lin = blockIdx.y * gx + blockIdx.x;
  if ((nwg & 7) == 0) lin = (lin & 7) * (nwg >> 3) + (lin >> 3);
  const int gm0 = (lin / gx) * BM;
  const int gn0 = (lin % gx) * BN;

  constexpr int FM = BM / 32;
  constexpr int FN = BN / 32;
  const int wr  = wave >> 1, wc = wave & 1;
  const int wm0 = wr * (BM / 2);
  const int wn0 = wc * (BN / 2);

  f32x4 acc[FM][FN];
  const f32x4 zero = {0.f, 0.f, 0.f, 0.f};
#pragma unroll
  for (int i = 0; i < FM; ++i)
#pragma unroll
    for (int j = 0; j < FN; ++j) acc[i][j] = zero;

  constexpr int NCA = BM * 8 / 256;
  constexpr int NCB = BN * 8 / 256;

  const int nkt = Ktot / BK;
  for (int kt = 0; kt < nkt; ++kt) {
    const int k0 = kt * BK;
    const bf16* Ap; int lda, ka;
    const bf16* Bp; int ldb, kb;
    if (k0 < K1) {
      Ap = A0;  lda = lda0; ka = k0;      Bp = B0;  ldb = ldb0; kb = k0;
    } else if (k0 < K2) {
      Ap = A1;  lda = lda1; ka = k0 - K1; Bp = B1;  ldb = ldb1; kb = k0 - K1;
    } else {
      Ap = A2p; lda = lda2; ka = k0 - K2; Bp = B2p; ldb = ldb2; kb = k0 - K2;
    }

    __syncthreads();

#pragma unroll
    for (int it = 0; it < NCA; ++it) {
      const int Cb = it * 256 + wave * 64;
      const int C  = Cb + lane;
      const int m  = C >> 3;
      const int jg = (C & 7) ^ (m & 7);
      async_cp16(Ap + (size_t)(gm0 + m) * lda + ka + jg * 8, &As[Cb * 8]);
    }
#pragma unroll
    for (int it = 0; it < NCB; ++it) {
      const int Cb = it * 256 + wave * 64;
      const int C  = Cb + lane;
      const int n  = C >> 3;
      const int jg = (C & 7) ^ (n & 7);
      async_cp16(Bp + (size_t)(gn0 + n) * ldb + kb + jg * 8, &Bs[Cb * 8]);
    }

    __syncthreads();

#pragma unroll
    for (int s = 0; s < 2; ++s) {
      bf16x8 af[FM], bfr[FN];
#pragma unroll
      for (int i = 0; i < FM; ++i) {
        const int m = wm0 + i * 16 + ml;
        const int j = (s * 4 + q) ^ (m & 7);
        af[i] = *(const bf16x8*)&As[(m * 8 + j) * 8];
      }
#pragma unroll
      for (int jn = 0; jn < FN; ++jn) {
        const int n = wn0 + jn * 16 + ml;
        const int j = (s * 4 + q) ^ (n & 7);
        bfr[jn] = *(const bf16x8*)&Bs[(n * 8 + j) * 8];
      }
#pragma unroll
      for (int i = 0; i < FM; ++i)
#pragma unroll
        for (int jn = 0; jn < FN; ++jn)
          acc[i][jn] = __builtin_amdgcn_mfma_f32_16x16x32_bf16(af[i], bfr[jn], acc[i][jn], 0, 0, 0);
    }
  }

#pragma unroll
  for (int i = 0; i < FM; ++i) {
#pragma unroll
    for (int jn = 0; jn < FN; ++jn) {
      const int row = gm0 + wm0 + i * 16 + q * 4;
      const int col = gn0 + wn0 + jn * 16 + ml;
#pragma unroll
      for (int r = 0; r < 4; ++r) {
        if constexpr (OUTMODE == 1)
          ((bf16*)Cout)[(size_t)(row + r) * ldc + col] = (bf16)acc[i][jn][r];
        else
          ((float*)Cout)[(size_t)(row + r) * ldc + col] = acc[i][jn][r];
      }
    }
  }
}

// One wave per token: fp32 gate logits (sum of ncomp 128-wide components in a
// gld-wide Gg row) -> exact top-2 softmax; scale the bf16 z values already
// sitting in A2[t][0:256] in-place; fill cols 256..319.
__global__ void router_kernel(const float* __restrict__ Gg, bf16* __restrict__ A2,
                              int gld, int ncomp) {
  const int wave = threadIdx.x >> 6, lane = threadIdx.x & 63;
  const int t = blockIdx.x * 4 + wave;
  const float* g = Gg + (size_t)t * gld;
  float g1 = 0.f, g2 = 0.f;
  for (int cc = 0; cc < ncomp; ++cc) {
    g1 += g[cc * 128 + lane];
    g2 += g[cc * 128 + 64 + lane];
  }
  float s1 = g1 * g1, s2 = g2 * g2;
#pragma unroll
  for (int off = 1; off < 16; off <<= 1) {
    s1 += __shfl_xor(s1, off, 64);
    s2 += __shfl_xor(s2, off, 64);
  }
  float lg[8];
#pragma unroll
  for (int e = 0; e < 4; ++e) {
    lg[e]     = sqrtf(__shfl(s1, e * 16, 64));
    lg[e + 4] = sqrtf(__shfl(s2, e * 16, 64));
  }
  int i1 = 0; float l1 = lg[0];
#pragma unroll
  for (int e = 1; e < 8; ++e) if (lg[e] > l1) { l1 = lg[e]; i1 = e; }
  int i2 = -1; float l2 = -1e30f;
#pragma unroll
  for (int e = 0; e < 8; ++e) if (e != i1 && lg[e] > l2) { l2 = lg[e]; i2 = e; }
  const float w1 = 1.f / (1.f + expf(l2 - l1));  // exact top-2 softmax renorm
  const float w2 = 1.f - w1;

  bf16* a2 = A2 + (size_t)t * A2C;
#pragma unroll
  for (int c0 = 0; c0 < A2C; c0 += 64) {
    const int c = c0 + lane;
    float v;
    if (c < 256) {
      const int we = c >> 5;
      const float wsel = (we == i1) ? w1 : ((we == i2) ? w2 : 0.f);
      v = (float)a2[c] * wsel;   // z (bf16, written by uni_gemm) scaled in place
    } else if (c < 264) {
      const int we = c - 256;
      v = (we == i1) ? w1 : ((we == i2) ? w2 : 0.f);
    } else if (c == 264) {
      v = 1.f;
    } else {
      v = 0.f;
    }
    a2[c] = (bf16)v;
  }
}

extern "C" void kernel_launch(void* const* d_in, const int* in_sizes, int n_in,
                              void* d_out, int out_size, void* d_ws, size_t ws_size,
                              hipStream_t stream) {
  // size-based dispatch; u/svh share 524288: first = u, second = svh (dict order)
  const float *x = nullptr, *W = nullptr, *b = nullptr, *gw = nullptr;
  const float *u = nullptr, *svh = nullptr, *eb = nullptr;
  int seen524 = 0;
  for (int i = 0; i < n_in; ++i) {
    switch (in_sizes[i]) {
      case 16777216: x  = (const float*)d_in[i]; break;
      case 4194304:  W  = (const float*)d_in[i]; break;
      case 2048:     b  = (const float*)d_in[i]; break;
      case 262144:   gw = (const float*)d_in[i]; break;
      case 524288:   if (seen524++ == 0) u = (const float*)d_in[i];
                     else                svh = (const float*)d_in[i];
                     break;
      case 16384:    eb = (const float*)d_in[i]; break;
      default: break;  // top_k (size 1)
    }
  }
  float* out = (float*)d_out;   // fp32 output (confirmed round 6)

  char* ws = (char*)d_ws;
  // Unified path needs 96.7 MB; fall back to the known-good 53.7 MB layout
  // with the fp32 VALU gate if the harness gave us less.
  const bool unified = (ws_size >= WS_U_TOTAL);

  if (unified) {
    bf16*  xbl = (bf16*)(ws + WS_U_XBL);
    float* Gg  = (float*)(ws + WS_U_GG);
    bf16*  A2  = (bf16*)(ws + WS_U_A2);
    bf16*  B2  = (bf16*)(ws + WS_U_B2);
    bf16*  Bp  = (bf16*)(ws + WS_U_BP);
    bf16*  Wb  = (bf16*)(ws + WS_U_WB);

    prep_kernel<<<1024, 256, 0, stream>>>(x, W, svh, u, eb, b, gw,
                                          xbl, Wb, Bp, B2, 1);

    // Uniform small GEMM: 640 identical 128x64-tile blocks, K=2048 each,
    // per-block operand select (see uni_gemm header). Direct stores.
    uni_gemm<<<640, 256, 0, stream>>>(xbl, Bp, Gg, A2);

    router_kernel<<<T_TOK / 4, 256, 0, stream>>>(Gg, A2, 384, 3);

    // out = [xh | A2] @ [Wb | B2]^T (pre + moe + both biases), fp32 store.
    // 256x128 tile, 4 waves, 64 MFMA/wave/K-step, 512 blocks exact fill.
    gemm_big2<<<512, 256, 0, stream>>>(
        xbl, XBL_LD, A2, A2C, Wb, IN_F, B2, A2C,
        out, OUT_F, IN_F, K2_TOT);
  } else {
    bf16*  xb = (bf16*)(ws + WS_F_XB);
    float* Gg = (float*)(ws + WS_F_GG);
    bf16*  A2 = (bf16*)(ws + WS_F_A2);
    bf16*  B2 = (bf16*)(ws + WS_F_B2);
    bf16*  Wz = (bf16*)(ws + WS_F_WZ);
    bf16*  Wb = (bf16*)(ws + WS_F_WB);

    prep_kernel<<<1024, 256, 0, stream>>>(x, W, svh, u, eb, b, gw,
                                          xb, Wb, Wz, B2, 0);

    hipMemsetAsync(Gg, 0, (size_t)T_TOK * GATE_N * 4, stream);
    vgemm_gate<<<dim3(2, T_TOK / 64, GATE_KS), 256, 0, stream>>>(x, gw, Gg);
    gemm_bt<64, 64, 1><<<dim3(Z_COLS / 64, T_TOK / 64), 256, 0, stream>>>(
        xb, IN_F, xb, IN_F, xb, IN_F, Wz, IN_F, Wz, IN_F, Wz, IN_F,
        (void*)A2, A2C, IN_F, IN_F, IN_F);

    router_kernel<<<T_TOK / 4, 256, 0, stream>>>(Gg, A2, 128, 1);

    gemm_bt<128, 128, 0><<<dim3(OUT_F / 128, T_TOK / 128), 256, 0, stream>>>(
        xb, IN_F, A2, A2C, A2, A2C, Wb, IN_F, B2, A2C, B2, A2C,
        (void*)out, OUT_F, IN_F, K2_TOT, K2_TOT);
  }
}